// Round 2
// baseline (23569.484 us; speedup 1.0000x reference)
//
#include <hip/hip_runtime.h>
#include <stdint.h>

#define B_  64
#define T_  2048
#define I_  256
#define H_  512
#define NG  4      // batch groups (16 batch each)
#define NP  8      // WGs per group, each owns HS h-elements
#define HS  64

typedef __attribute__((ext_vector_type(8))) short  short8;
typedef __attribute__((ext_vector_type(4))) float  floatx4;

__device__ __forceinline__ unsigned short f2bf(float f) {
    unsigned u = __float_as_uint(f);
    u = (u + 0x7fffu + ((u >> 16) & 1u)) >> 16;   // RNE
    return (unsigned short)u;
}

__device__ __forceinline__ short8 ld8_bf(const float* p) {
    floatx4 a = *(const floatx4*)p;
    floatx4 c = *(const floatx4*)(p + 4);
    short8 r;
    r[0] = (short)f2bf(a[0]); r[1] = (short)f2bf(a[1]);
    r[2] = (short)f2bf(a[2]); r[3] = (short)f2bf(a[3]);
    r[4] = (short)f2bf(c[0]); r[5] = (short)f2bf(c[1]);
    r[6] = (short)f2bf(c[2]); r[7] = (short)f2bf(c[3]);
    return r;
}

__device__ __forceinline__ float sigf(float x) { return 1.f / (1.f + __expf(-x)); }
__device__ __forceinline__ float tanh_(float x) { return 2.f * sigf(2.f * x) - 1.f; }

__global__ __launch_bounds__(256, 1) void gru_persist(
    const float* __restrict__ xs, const float* __restrict__ w_ih,
    const float* __restrict__ w_hh, const float* __restrict__ b,
    const float* __restrict__ b_n, float* __restrict__ out,
    unsigned* __restrict__ flags, unsigned short* __restrict__ hpub)
{
    const int tid  = threadIdx.x;
    const int wv   = tid >> 6;          // wave 0..3 -> h-tile within slice
    const int lane = tid & 63;
    const int q    = lane >> 4;         // quad 0..3
    const int c    = lane & 15;         // col: batch within group / row within A-tile
    const int g    = blockIdx.x & (NG - 1);
    const int p    = blockIdx.x >> 2;   // 0..7 slice owner within group
    const int hbase = p * HS + wv * 16; // this wave's 16 h-rows
    const int batch = g * 16 + c;

    // ---- weight preload: A-fragments resident in VGPRs ----
    // A-frag layout (16x16x32): lane holds A[m=lane&15][k = quad*8 + j]
    short8 whh[3][16];  // 3 gates x 16 k-tiles over H=512
    short8 wih[3][8];   // 3 gates x  8 k-tiles over I=256
#pragma unroll
    for (int gate = 0; gate < 3; ++gate) {
        const float* wr = w_hh + (size_t)(gate * H_ + hbase + c) * H_ + q * 8;
#pragma unroll
        for (int kt = 0; kt < 16; ++kt) whh[gate][kt] = ld8_bf(wr + kt * 32);
        const float* wi = w_ih + (size_t)(gate * H_ + hbase + c) * I_ + q * 8;
#pragma unroll
        for (int kt = 0; kt < 8; ++kt)  wih[gate][kt] = ld8_bf(wi + kt * 32);
    }
    // biases at this lane's C/D rows: row = quad*4 + i
    float br[4], bz[4], bni[4], bnn[4];
#pragma unroll
    for (int i = 0; i < 4; ++i) {
        int j = hbase + q * 4 + i;
        br[i]  = b[j];
        bz[i]  = b[H_ + j];
        bni[i] = b[2 * H_ + j];
        bnn[i] = b_n[j];
    }
    float hown[4] = {0.f, 0.f, 0.f, 0.f};   // fp32 master h at (row=q*4+i, col=c)

    const int myflag = (g * NP + p) * 16;

    for (int t = 0; t < T_; ++t) {
        // ---- input-gate GEMM: independent of h, overlaps peer sync ----
        const float* xrow = xs + ((size_t)batch * T_ + t) * I_ + q * 8;
        short8 bx[8];
#pragma unroll
        for (int kt = 0; kt < 8; ++kt) bx[kt] = ld8_bf(xrow + kt * 32);

        floatx4 accr  = {br[0],  br[1],  br[2],  br[3]};
        floatx4 accz  = {bz[0],  bz[1],  bz[2],  bz[3]};
        floatx4 accni = {bni[0], bni[1], bni[2], bni[3]};
        floatx4 accnh = {0.f, 0.f, 0.f, 0.f};
#pragma unroll
        for (int kt = 0; kt < 8; ++kt) {
            accr  = __builtin_amdgcn_mfma_f32_16x16x32_bf16(wih[0][kt], bx[kt], accr,  0, 0, 0);
            accz  = __builtin_amdgcn_mfma_f32_16x16x32_bf16(wih[1][kt], bx[kt], accz,  0, 0, 0);
            accni = __builtin_amdgcn_mfma_f32_16x16x32_bf16(wih[2][kt], bx[kt], accni, 0, 0, 0);
        }

        // ---- wait for all peers to have published h_t ----
        if (tid < NP) {
            while ((int)__hip_atomic_load(&flags[(g * NP + tid) * 16],
                       __ATOMIC_RELAXED, __HIP_MEMORY_SCOPE_AGENT) < t)
                __builtin_amdgcn_s_sleep(1);
        }
        __syncthreads();
        __builtin_amdgcn_fence(__ATOMIC_ACQUIRE, "agent");

        // ---- recurrent GEMM: h_t published as bf16 [2][B][H], B-frag friendly ----
        const unsigned short* hrow =
            hpub + ((size_t)(t & 1) * B_ + batch) * H_ + q * 8;
#pragma unroll
        for (int kt = 0; kt < 16; ++kt) {
            short8 bh = *(const short8*)(hrow + kt * 32);
            accr  = __builtin_amdgcn_mfma_f32_16x16x32_bf16(whh[0][kt], bh, accr,  0, 0, 0);
            accz  = __builtin_amdgcn_mfma_f32_16x16x32_bf16(whh[1][kt], bh, accz,  0, 0, 0);
            accnh = __builtin_amdgcn_mfma_f32_16x16x32_bf16(whh[2][kt], bh, accnh, 0, 0, 0);
        }

        // ---- gates (lane-local: C-layout rows match across the 4 accumulators) ----
#pragma unroll
        for (int i = 0; i < 4; ++i) {
            float r = sigf(accr[i]);
            float z = sigf(accz[i]);
            float n = tanh_(accni[i] + r * (accnh[i] + bnn[i]));
            hown[i] = n + z * (hown[i] - n);
        }

        if (t + 1 < T_) {
            // publish own slice as bf16 into buf[(t+1)&1]; rows q*4..q*4+3 are
            // consecutive h-indices -> one 8B store per lane
            ushort4 pk;
            pk.x = f2bf(hown[0]); pk.y = f2bf(hown[1]);
            pk.z = f2bf(hown[2]); pk.w = f2bf(hown[3]);
            *(ushort4*)(hpub + ((size_t)((t + 1) & 1) * B_ + batch) * H_ + hbase + q * 4) = pk;
            __builtin_amdgcn_fence(__ATOMIC_RELEASE, "agent");
            __syncthreads();
            if (tid == 0)
                __hip_atomic_store(&flags[myflag], (unsigned)(t + 1),
                                   __ATOMIC_RELAXED, __HIP_MEMORY_SCOPE_AGENT);
        }
    }

    // ---- final h (fp32) ----
    floatx4 o = {hown[0], hown[1], hown[2], hown[3]};
    *(floatx4*)(out + (size_t)batch * H_ + hbase + q * 4) = o;
}

extern "C" void kernel_launch(void* const* d_in, const int* in_sizes, int n_in,
                              void* d_out, int out_size, void* d_ws, size_t ws_size,
                              hipStream_t stream) {
    (void)in_sizes; (void)n_in; (void)out_size; (void)ws_size;
    const float* xs   = (const float*)d_in[0];
    const float* w_ih = (const float*)d_in[1];
    const float* w_hh = (const float*)d_in[2];
    const float* b    = (const float*)d_in[3];
    const float* b_n  = (const float*)d_in[4];
    float* out = (float*)d_out;

    unsigned*       flags = (unsigned*)d_ws;                       // 2KB used
    unsigned short* hpub  = (unsigned short*)((char*)d_ws + 4096); // 2*64*512*2 = 128KB

    // zero flags + h0 double-buffer (ws is poisoned 0xAA before every call)
    (void)hipMemsetAsync(d_ws, 0, 4096 + 2 * B_ * H_ * sizeof(unsigned short), stream);

    gru_persist<<<NG * NP, 256, 0, stream>>>(xs, w_ih, w_hh, b, b_n, out, flags, hpub);
}

// Round 3
// 21206.679 us; speedup vs baseline: 1.1114x; 1.1114x over previous
//
#include <hip/hip_runtime.h>
#include <stdint.h>

#define B_  64
#define T_  2048
#define I_  256
#define H_  512
#define NG  4      // batch groups (16 batch each)
#define NP  8      // WGs per group, each owns HS h-elements
#define HS  64

typedef __attribute__((ext_vector_type(8))) short  short8;
typedef __attribute__((ext_vector_type(4))) float  floatx4;
typedef unsigned long long u64;

__device__ __forceinline__ unsigned short f2bf(float f) {
    unsigned u = __float_as_uint(f);
    u = (u + 0x7fffu + ((u >> 16) & 1u)) >> 16;   // RNE
    return (unsigned short)u;
}

__device__ __forceinline__ short8 ld8_bf(const float* p) {
    floatx4 a = *(const floatx4*)p;
    floatx4 c = *(const floatx4*)(p + 4);
    short8 r;
    r[0] = (short)f2bf(a[0]); r[1] = (short)f2bf(a[1]);
    r[2] = (short)f2bf(a[2]); r[3] = (short)f2bf(a[3]);
    r[4] = (short)f2bf(c[0]); r[5] = (short)f2bf(c[1]);
    r[6] = (short)f2bf(c[2]); r[7] = (short)f2bf(c[3]);
    return r;
}

__device__ __forceinline__ float sigf(float x) { return 1.f / (1.f + __expf(-x)); }
__device__ __forceinline__ float tanh_(float x) { return 2.f * sigf(2.f * x) - 1.f; }

__global__ __launch_bounds__(256, 1) void gru_persist(
    const float* __restrict__ xs, const float* __restrict__ w_ih,
    const float* __restrict__ w_hh, const float* __restrict__ b,
    const float* __restrict__ b_n, float* __restrict__ out,
    unsigned* __restrict__ flags, unsigned short* __restrict__ hpub)
{
    const int tid  = threadIdx.x;
    const int wv   = tid >> 6;          // wave 0..3 -> h-tile within slice
    const int lane = tid & 63;
    const int q    = lane >> 4;         // quad 0..3
    const int c    = lane & 15;         // col: batch within group / row within A-tile
    const int g    = blockIdx.x & (NG - 1);
    const int p    = blockIdx.x >> 2;   // 0..7 slice owner within group
    const int hbase = p * HS + wv * 16; // this wave's 16 h-rows
    const int batch = g * 16 + c;

    // ---- weight preload: A-fragments resident in VGPRs/AGPRs ----
    short8 whh[3][16];  // 3 gates x 16 k-tiles over H=512
    short8 wih[3][8];   // 3 gates x  8 k-tiles over I=256
#pragma unroll
    for (int gate = 0; gate < 3; ++gate) {
        const float* wr = w_hh + (size_t)(gate * H_ + hbase + c) * H_ + q * 8;
#pragma unroll
        for (int kt = 0; kt < 16; ++kt) whh[gate][kt] = ld8_bf(wr + kt * 32);
        const float* wi = w_ih + (size_t)(gate * H_ + hbase + c) * I_ + q * 8;
#pragma unroll
        for (int kt = 0; kt < 8; ++kt)  wih[gate][kt] = ld8_bf(wi + kt * 32);
    }
    float br[4], bz[4], bni[4], bnn[4];
#pragma unroll
    for (int i = 0; i < 4; ++i) {
        int j = hbase + q * 4 + i;
        br[i]  = b[j];
        bz[i]  = b[H_ + j];
        bni[i] = b[2 * H_ + j];
        bnn[i] = b_n[j];
    }
    float hown[4] = {0.f, 0.f, 0.f, 0.f};   // fp32 master h at (row=q*4+i, col=c)

    const int myflag = (g * NP + p) * 16;

    for (int t = 0; t < T_; ++t) {
        // ---- input-gate GEMM: independent of h, overlaps peer wait ----
        const float* xrow = xs + ((size_t)batch * T_ + t) * I_ + q * 8;
        short8 bx[8];
#pragma unroll
        for (int kt = 0; kt < 8; ++kt) bx[kt] = ld8_bf(xrow + kt * 32);

        floatx4 accr  = {br[0],  br[1],  br[2],  br[3]};
        floatx4 accz  = {bz[0],  bz[1],  bz[2],  bz[3]};
        floatx4 accni = {bni[0], bni[1], bni[2], bni[3]};
        floatx4 accnh = {0.f, 0.f, 0.f, 0.f};
#pragma unroll
        for (int kt = 0; kt < 8; ++kt) {
            accr  = __builtin_amdgcn_mfma_f32_16x16x32_bf16(wih[0][kt], bx[kt], accr,  0, 0, 0);
            accz  = __builtin_amdgcn_mfma_f32_16x16x32_bf16(wih[1][kt], bx[kt], accz,  0, 0, 0);
            accni = __builtin_amdgcn_mfma_f32_16x16x32_bf16(wih[2][kt], bx[kt], accni, 0, 0, 0);
        }

        // ---- wait for all peers to have published h_t (coherent dword loads,
        //      no cache-wide fence) ----
        if (tid < NP) {
            while ((int)__hip_atomic_load(&flags[(g * NP + tid) * 16],
                       __ATOMIC_RELAXED, __HIP_MEMORY_SCOPE_AGENT) < t)
                __builtin_amdgcn_s_sleep(1);
        }
        __syncthreads();
        asm volatile("" ::: "memory");  // compiler barrier only (no buffer_inv)

        // ---- recurrent GEMM: h_t read as coherent (sc0 sc1) 8B loads ----
        const u64* hq = (const u64*)(hpub + ((size_t)(t & 1) * B_ + batch) * H_ + q * 8);
#pragma unroll
        for (int kt = 0; kt < 16; ++kt) {
            union { u64 u[2]; short8 s; } cv;
            cv.u[0] = __hip_atomic_load(hq + kt * 8,     __ATOMIC_RELAXED, __HIP_MEMORY_SCOPE_AGENT);
            cv.u[1] = __hip_atomic_load(hq + kt * 8 + 1, __ATOMIC_RELAXED, __HIP_MEMORY_SCOPE_AGENT);
            short8 bh = cv.s;
            accr  = __builtin_amdgcn_mfma_f32_16x16x32_bf16(whh[0][kt], bh, accr,  0, 0, 0);
            accz  = __builtin_amdgcn_mfma_f32_16x16x32_bf16(whh[1][kt], bh, accz,  0, 0, 0);
            accnh = __builtin_amdgcn_mfma_f32_16x16x32_bf16(whh[2][kt], bh, accnh, 0, 0, 0);
        }

        // ---- gates (lane-local) ----
#pragma unroll
        for (int i = 0; i < 4; ++i) {
            float r = sigf(accr[i]);
            float z = sigf(accz[i]);
            float n = tanh_(accni[i] + r * (accnh[i] + bnn[i]));
            hown[i] = n + z * (hown[i] - n);
        }

        if (t + 1 < T_) {
            // publish own slice as one coherent 8B store per lane
            u64 pk = (u64)f2bf(hown[0])
                   | ((u64)f2bf(hown[1]) << 16)
                   | ((u64)f2bf(hown[2]) << 32)
                   | ((u64)f2bf(hown[3]) << 48);
            u64* dst = (u64*)(hpub + ((size_t)((t + 1) & 1) * B_ + batch) * H_ + hbase + q * 4);
            __hip_atomic_store(dst, pk, __ATOMIC_RELAXED, __HIP_MEMORY_SCOPE_AGENT);
            // order: h-store ack from coherence point BEFORE flag store
            asm volatile("s_waitcnt vmcnt(0)" ::: "memory");
            __syncthreads();
            if (tid == 0)
                __hip_atomic_store(&flags[myflag], (unsigned)(t + 1),
                                   __ATOMIC_RELAXED, __HIP_MEMORY_SCOPE_AGENT);
        }
    }

    // ---- final h (fp32) ----
    floatx4 o = {hown[0], hown[1], hown[2], hown[3]};
    *(floatx4*)(out + (size_t)batch * H_ + hbase + q * 4) = o;
}

extern "C" void kernel_launch(void* const* d_in, const int* in_sizes, int n_in,
                              void* d_out, int out_size, void* d_ws, size_t ws_size,
                              hipStream_t stream) {
    (void)in_sizes; (void)n_in; (void)out_size; (void)ws_size;
    const float* xs   = (const float*)d_in[0];
    const float* w_ih = (const float*)d_in[1];
    const float* w_hh = (const float*)d_in[2];
    const float* b    = (const float*)d_in[3];
    const float* b_n  = (const float*)d_in[4];
    float* out = (float*)d_out;

    unsigned*       flags = (unsigned*)d_ws;                       // 2KB used
    unsigned short* hpub  = (unsigned short*)((char*)d_ws + 4096); // 2*64*512*2 = 128KB

    // zero flags + h double-buffer (ws is poisoned 0xAA before every call)
    (void)hipMemsetAsync(d_ws, 0, 4096 + 2 * B_ * H_ * sizeof(unsigned short), stream);

    gru_persist<<<NG * NP, 256, 0, stream>>>(xs, w_ih, w_hh, b, b_n, out, flags, hpub);
}